// Round 13
// baseline (140.421 us; speedup 1.0000x reference)
//
#include <hip/hip_runtime.h>
#include <cstdint>

#define E_CNT 131072
#define N_CNT 4096

typedef short bf16x8 __attribute__((ext_vector_type(8)));
typedef float f32x4 __attribute__((ext_vector_type(4)));

__device__ __forceinline__ ushort f2bf(float f) {
  union { float f; unsigned u; } v; v.f = f;
  unsigned r = v.u + 0x7FFFu + ((v.u >> 16) & 1u);
  return (ushort)(r >> 16);
}

// ---- prep: W1 combine+T | root1^T | deg | W2 combine | cvt_x -------------
// [0,256):    wt1[r*64+o][i] = f2bf(sum_b att1[r,b]*basis1[b,i,o]), r<8
// [256,384):  root1^T -> wt1 rows 512..575
// [384,896):  degree histogram
// [896,905):  w2e combine (9 blocks)
// [905,9097): x fp32->bf16, 8 floats/thread
__global__ __launch_bounds__(256) void k_prep(const float* __restrict__ att1,
                                              const float* __restrict__ basis1,
                                              const float* __restrict__ root1,
                                              ushort* __restrict__ wt1,
                                              const int* __restrict__ dstp,
                                              int* __restrict__ deg,
                                              const float* __restrict__ att2,
                                              const float* __restrict__ basis2,
                                              const float* __restrict__ root2,
                                              float* __restrict__ w2e,
                                              const float4* __restrict__ x,
                                              ushort* __restrict__ xbf) {
  __shared__ float sT[32 * 33];
  int bid = blockIdx.x, t = threadIdx.x;
  if (bid < 256) {
    int i0 = (bid >> 1) * 32, o0 = (bid & 1) * 32;
    int ol = t & 31, ir = t >> 5;      // ir = 0..7
    float a[8][4] = {};
    for (int b = 0; b < 30; b += 2) {  // unroll x2: 8 loads in flight
      float v0[4], v1[4];
#pragma unroll
      for (int k = 0; k < 4; ++k) {
        size_t ofs = (size_t)(i0 + ir + k * 8) * 64 + o0 + ol;
        v0[k] = basis1[(size_t)b * 262144 + ofs];
        v1[k] = basis1[(size_t)(b + 1) * 262144 + ofs];
      }
#pragma unroll
      for (int r = 0; r < 8; ++r) {
        float w0 = att1[r * 30 + b], w1 = att1[r * 30 + b + 1];
#pragma unroll
        for (int k = 0; k < 4; ++k) a[r][k] += w0 * v0[k] + w1 * v1[k];
      }
    }
    for (int r = 0; r < 8; ++r) {
#pragma unroll
      for (int k = 0; k < 4; ++k) sT[ol * 33 + ir + k * 8] = a[r][k];
      __syncthreads();
#pragma unroll
      for (int k = 0; k < 4; ++k) {
        int orow = ir + k * 8, icol = ol;
        wt1[(size_t)(r * 64 + o0 + orow) * 4096 + i0 + icol] = f2bf(sT[orow * 33 + icol]);
      }
      __syncthreads();
    }
  } else if (bid < 384) {
    int bb = bid - 256;                // 128 blocks: 32 i-rows each
    int i0 = bb * 32;
    int ol = t & 31, ir = t >> 5;
    for (int oh = 0; oh < 2; ++oh) {
      int o0 = oh * 32;
#pragma unroll
      for (int k = 0; k < 4; ++k)
        sT[ol * 33 + ir + k * 8] = root1[(size_t)(i0 + ir + k * 8) * 64 + o0 + ol];
      __syncthreads();
#pragma unroll
      for (int k = 0; k < 4; ++k) {
        int orow = ir + k * 8, icol = ol;
        wt1[(size_t)(512 + o0 + orow) * 4096 + i0 + icol] = f2bf(sT[orow * 33 + icol]);
      }
      __syncthreads();
    }
  } else if (bid < 896) {
    int e = (bid - 384) * 256 + t;
    atomicAdd(&deg[dstp[e]], 1);
  } else if (bid < 905) {
    int r = bid - 896;  // 0..8
    for (int q = t; q < 1024; q += 256) {
      float a = 0.f;
      if (r < 8) {
        for (int b = 0; b < 30; ++b) a += att2[r * 30 + b] * basis2[b * 1024 + q];
      } else {
        a = root2[q];
      }
      w2e[r * 1024 + q] = a;
    }
  } else {
    int i = (bid - 905) * 256 + t;     // 8 floats / thread
    float4 v0 = x[i * 2], v1 = x[i * 2 + 1];
    ushort o[8];
    o[0] = f2bf(v0.x); o[1] = f2bf(v0.y); o[2] = f2bf(v0.z); o[3] = f2bf(v0.w);
    o[4] = f2bf(v1.x); o[5] = f2bf(v1.y); o[6] = f2bf(v1.z); o[7] = f2bf(v1.w);
    *(ulonglong2*)(xbf + (size_t)i * 8) = *(const ulonglong2*)o;
  }
}

// ---------------- GEMM (frozen R5 config, measured 48.4us) ----------------
// BM=128 BN=64 BK=64, SPLITK=4 (16 K-steps), 256 thr (2x2 waves, 64x32/wave).
// Single-buffer 24KB LDS, 2-barrier loop, chunk-XOR swizzle both sides,
// 8x144 bijective XCD swizzle, atomic f32 epilogue into zeroed c1.
__global__ __launch_bounds__(256, 5) void k_gemm1(const ushort* __restrict__ xbf,
                                                  const ushort* __restrict__ wt1,
                                                  float* __restrict__ c1) {
  __shared__ __align__(16) ushort As[128 * 64];
  __shared__ __align__(16) ushort Bs[64 * 64];
  int bid = blockIdx.x;
  int swz = (bid & 7) * 144 + (bid >> 3);  // 1152 = 8*144, bijective
  int kp = swz / 288, rem = swz % 288;
  int bm = rem / 9, bn = rem % 9;
  int m0 = bm * 128, n0 = bn * 64, kbase = kp * 1024;
  int tid = threadIdx.x;
  int lane = tid & 63, wid = tid >> 6;
  int wm = wid >> 1, wn = wid & 1;

  f32x4 acc[4][2] = {};

  for (int tt = 0; tt < 16; ++tt) {
    int k0 = kbase + tt * 64;
#pragma unroll
    for (int it = 0; it < 4; ++it) {
      int flat = it * 256 + tid;
      int row = flat >> 3, gg = flat & 7;
      int gcol = k0 + ((gg ^ (row & 7)) << 3);  // pre-swizzled global source
      const ushort* g = xbf + (size_t)(m0 + row) * 4096 + gcol;
      ushort* l = &As[(it * 256 + wid * 64) * 8];  // linear LDS dest
      __builtin_amdgcn_global_load_lds((const __attribute__((address_space(1))) void*)g,
                                       (__attribute__((address_space(3))) void*)l, 16, 0, 0);
    }
#pragma unroll
    for (int it = 0; it < 2; ++it) {
      int flat = it * 256 + tid;
      int row = flat >> 3, gg = flat & 7;
      int gcol = k0 + ((gg ^ (row & 7)) << 3);
      const ushort* g = wt1 + (size_t)(n0 + row) * 4096 + gcol;
      ushort* l = &Bs[(it * 256 + wid * 64) * 8];
      __builtin_amdgcn_global_load_lds((const __attribute__((address_space(1))) void*)g,
                                       (__attribute__((address_space(3))) void*)l, 16, 0, 0);
    }
    __syncthreads();  // vmcnt(0) drain: all waves' stage landed
    int q = lane >> 4, sw = lane & 7, r16 = lane & 15;
#pragma unroll
    for (int ks = 0; ks < 2; ++ks) {
      int co = ((ks * 4 + q) ^ sw) << 3;
      bf16x8 b0 = *(const bf16x8*)&Bs[(wn * 32 + 0 * 16 + r16) * 64 + co];
      bf16x8 b1 = *(const bf16x8*)&Bs[(wn * 32 + 1 * 16 + r16) * 64 + co];
      bf16x8 a0 = *(const bf16x8*)&As[(wm * 64 + 0 * 16 + r16) * 64 + co];
      bf16x8 a1 = *(const bf16x8*)&As[(wm * 64 + 1 * 16 + r16) * 64 + co];
      bf16x8 a2 = *(const bf16x8*)&As[(wm * 64 + 2 * 16 + r16) * 64 + co];
      bf16x8 a3 = *(const bf16x8*)&As[(wm * 64 + 3 * 16 + r16) * 64 + co];
      __builtin_amdgcn_s_setprio(1);
      acc[0][0] = __builtin_amdgcn_mfma_f32_16x16x32_bf16(a0, b0, acc[0][0], 0, 0, 0);
      acc[0][1] = __builtin_amdgcn_mfma_f32_16x16x32_bf16(a0, b1, acc[0][1], 0, 0, 0);
      acc[1][0] = __builtin_amdgcn_mfma_f32_16x16x32_bf16(a1, b0, acc[1][0], 0, 0, 0);
      acc[1][1] = __builtin_amdgcn_mfma_f32_16x16x32_bf16(a1, b1, acc[1][1], 0, 0, 0);
      acc[2][0] = __builtin_amdgcn_mfma_f32_16x16x32_bf16(a2, b0, acc[2][0], 0, 0, 0);
      acc[2][1] = __builtin_amdgcn_mfma_f32_16x16x32_bf16(a2, b1, acc[2][1], 0, 0, 0);
      acc[3][0] = __builtin_amdgcn_mfma_f32_16x16x32_bf16(a3, b0, acc[3][0], 0, 0, 0);
      acc[3][1] = __builtin_amdgcn_mfma_f32_16x16x32_bf16(a3, b1, acc[3][1], 0, 0, 0);
      __builtin_amdgcn_s_setprio(0);
    }
    __syncthreads();  // LDS free for next stage
  }

  int cf = lane & 15, rf4 = (lane >> 4) * 4;
#pragma unroll
  for (int mi = 0; mi < 4; ++mi)
#pragma unroll
    for (int ni = 0; ni < 2; ++ni) {
      int gcol = n0 + wn * 32 + ni * 16 + cf;
#pragma unroll
      for (int j = 0; j < 4; ++j) {
        int grow = m0 + wm * 64 + mi * 16 + rf4 + j;
        atomicAdd(&c1[(size_t)grow * 576 + gcol], acc[mi][ni][j]);
      }
    }
}

// ---- layer-1 edge-parallel scatter: agg[dst][t] += c1[src][et*64+t] ------
// wave per edge-chunk, lane = feature. 2048 blocks x 4 waves = 8192 waves,
// 16 edges/wave. Coalesced 256B read + 256B atomic per edge.
__global__ __launch_bounds__(256) void k_sc1(const int* __restrict__ srcp,
                                             const int* __restrict__ dstp,
                                             const int* __restrict__ et,
                                             const float* __restrict__ c1,
                                             float* __restrict__ agg) {
  int wv = (blockIdx.x * 256 + threadIdx.x) >> 6;
  int lane = threadIdx.x & 63;
  int e0 = wv * 16;
#pragma unroll 4
  for (int e = e0; e < e0 + 16; ++e) {
    int s = srcp[e], d = dstp[e], r = et[e];
    float v = c1[(size_t)s * 576 + r * 64 + lane];
    atomicAdd(&agg[(size_t)d * 64 + lane], v);
  }
}

// ---- node kernel: h = relu(agg*dinv + root + bias1); h2c = h @ W2e -------
__global__ __launch_bounds__(256) void k_h(const float* __restrict__ agg,
                                           const int* __restrict__ deg,
                                           const float* __restrict__ c1,
                                           const float* __restrict__ bias1,
                                           const float* __restrict__ w2e,
                                           float* __restrict__ h2c) {
  __shared__ float sh[4][64];
  int g = threadIdx.x >> 6, t = threadIdx.x & 63;
  int n = blockIdx.x * 4 + g;
  float dinv = 1.0f / fmaxf((float)deg[n], 1.0f);
  float v = agg[(size_t)n * 64 + t] * dinv + c1[(size_t)n * 576 + 512 + t] + bias1[t];
  sh[g][t] = fmaxf(v, 0.f);
  __syncthreads();
  float* o = h2c + (size_t)n * 144;
  for (int rc = t; rc < 144; rc += 64) {
    int r9 = rc >> 4, c = rc & 15;
    const float* w = w2e + r9 * 1024 + c;
    float a = 0.f;
#pragma unroll
    for (int hh = 0; hh < 64; ++hh) a += sh[g][hh] * w[hh * 16];
    o[rc] = a;
  }
}

// ---- layer-2 edge scatter: outagg[dst][c] += h2c[src][et*16+c] -----------
// 4 edges per wave iteration (16-lane groups). 1024 blocks x 4 waves,
// 32 edges/wave.
__global__ __launch_bounds__(256) void k_sc2(const int* __restrict__ srcp,
                                             const int* __restrict__ dstp,
                                             const int* __restrict__ et,
                                             const float* __restrict__ h2c,
                                             float* __restrict__ outagg) {
  int wv = (blockIdx.x * 256 + threadIdx.x) >> 6;
  int lane = threadIdx.x & 63;
  int sub = lane >> 4, c = lane & 15;
  int e0 = wv * 32;
  for (int e = e0 + sub; e < e0 + 32; e += 4) {
    int s = srcp[e], d = dstp[e], r = et[e];
    float v = h2c[(size_t)s * 144 + r * 16 + c];
    atomicAdd(&outagg[(size_t)d * 16 + c], v);
  }
}

// ---- final: out = log_softmax(outagg*dinv + root2part + bias2) -----------
// 16 nodes per block (16 lanes per node).
__global__ __launch_bounds__(256) void k_out(const float* __restrict__ outagg,
                                             const int* __restrict__ deg,
                                             const float* __restrict__ h2c,
                                             const float* __restrict__ bias2,
                                             float* __restrict__ out) {
  int t = threadIdx.x;
  int n = blockIdx.x * 16 + (t >> 4);
  int c = t & 15;
  float dinv = 1.0f / fmaxf((float)deg[n], 1.0f);
  float v = outagg[(size_t)n * 16 + c] * dinv + h2c[(size_t)n * 144 + 128 + c] + bias2[c];
  float m = v;
#pragma unroll
  for (int off = 1; off < 16; off <<= 1) m = fmaxf(m, __shfl_xor(m, off, 64));
  float ex = expf(v - m);
  float s = ex;
#pragma unroll
  for (int off = 1; off < 16; off <<= 1) s += __shfl_xor(s, off, 64);
  out[(size_t)n * 16 + c] = v - m - logf(s);
}

extern "C" void kernel_launch(void* const* d_in, const int* in_sizes, int n_in,
                              void* d_out, int out_size, void* d_ws, size_t ws_size,
                              hipStream_t stream) {
  const float* x      = (const float*)d_in[0];
  const int*   ei     = (const int*)d_in[1];
  const int*   et     = (const int*)d_in[2];
  const float* basis1 = (const float*)d_in[3];
  const float* att1   = (const float*)d_in[4];
  const float* root1  = (const float*)d_in[5];
  const float* bias1  = (const float*)d_in[6];
  const float* basis2 = (const float*)d_in[7];
  const float* att2   = (const float*)d_in[8];
  const float* root2  = (const float*)d_in[9];
  const float* bias2  = (const float*)d_in[10];
  float* out = (float*)d_out;

  char* ws = (char*)d_ws;
  size_t off = 0;
  auto alloc = [&](size_t bytes) {
    void* p = ws + off;
    off = (off + bytes + 255) & ~(size_t)255;
    return p;
  };
  // zeroed region first (one memset): c1 | agg | outagg | deg
  float* c1     = (float*)alloc((size_t)N_CNT * 576 * 4);   // 9.44 MB
  float* agg    = (float*)alloc((size_t)N_CNT * 64 * 4);    // 1 MB
  float* outagg = (float*)alloc((size_t)N_CNT * 16 * 4);    // 256 KB
  int*   deg    = (int*)alloc(4096 * 4);                    // 16 KB
  size_t zbytes = off;
  ushort* xbf = (ushort*)alloc((size_t)N_CNT * N_CNT * 2);
  ushort* wt1 = (ushort*)alloc((size_t)576 * 4096 * 2);
  float*  w2e = (float*)alloc((size_t)9 * 64 * 16 * 4);
  float*  h2c = (float*)alloc((size_t)N_CNT * 144 * 4);

  const int* srcp = ei;
  const int* dstp = ei + E_CNT;

  hipMemsetAsync(c1, 0, zbytes, stream);
  k_prep<<<9097, 256, 0, stream>>>(att1, basis1, root1, wt1, dstp, deg,
                                   att2, basis2, root2, w2e,
                                   (const float4*)x, xbf);
  k_gemm1<<<1152, 256, 0, stream>>>(xbf, wt1, c1);
  k_sc1<<<2048, 256, 0, stream>>>(srcp, dstp, et, c1, agg);
  k_h<<<1024, 256, 0, stream>>>(agg, deg, c1, bias1, w2e, h2c);
  k_sc2<<<1024, 256, 0, stream>>>(srcp, dstp, et, h2c, outagg);
  k_out<<<256, 256, 0, stream>>>(outagg, deg, h2c, bias2, out);
}